// Round 1
// baseline (1151.905 us; speedup 1.0000x reference)
//
#include <hip/hip_runtime.h>
#include <math.h>

// Problem constants
// A=32, B=16, C=16, D=16, K=3, KK=9, KKA=288, NF=145, BSZ=4, H=W=14, L=196, BL=784

// ---------------------------------------------------------------------------
// Kernel 0: h table.  freq_filter == x + circular_conv(h_d, x) where
// h_d[t] = (1/288)(wr[0,d] + (-1)^t wr[144,d]
//                  + 2*sum_{f=1}^{143} (wr[f,d] cos(2pi f t/288) - wi[f,d] sin(2pi f t/288)))
// Stored doubled: h2[d][t] for t in [0,576), h2[t+288] = h2[t].
// ---------------------------------------------------------------------------
__global__ __launch_bounds__(256) void k_htab(const float* __restrict__ cw,
                                              float* __restrict__ h2) {
  int d = blockIdx.x;
  for (int t = threadIdx.x; t < 288; t += 256) {
    float acc = cw[(0 * 16 + d) * 2 + 0] +
                ((t & 1) ? -1.f : 1.f) * cw[(144 * 16 + d) * 2 + 0];
    for (int f = 1; f < 144; ++f) {
      int m = (f * t) % 288;                      // exact angle reduction
      float th = (float)m * (6.283185307179586f / 288.f);
      float sn, cs;
      sincosf(th, &sn, &cs);
      acc += 2.f * (cw[(f * 16 + d) * 2 + 0] * cs - cw[(f * 16 + d) * 2 + 1] * sn);
    }
    float h = acc * (1.f / 288.f);
    h2[d * 576 + t] = h;
    h2[d * 576 + t + 288] = h;
  }
}

// ---------------------------------------------------------------------------
// Kernel 1: per-row prep. One block per (b,l) row.
// Produces: a_out (first output), ws_pu [row][n][c], ws_co (coeff) [row][n][B].
// ---------------------------------------------------------------------------
__global__ __launch_bounds__(256) void k_rowprep(
    const float* __restrict__ a_img, const float* __restrict__ pose,
    const float* __restrict__ cpose2_w, const float* __restrict__ cpose2_b,
    const float* __restrict__ ln_g, const float* __restrict__ ln_b,
    const float* __restrict__ sp_w, const float* __restrict__ sp_b,
    float* __restrict__ out_a, float* __restrict__ ws_pu,
    float* __restrict__ ws_co) {
  __shared__ float s_pu[288 * 17];   // [n][c] pad 17
  __shared__ float s_lg[288 * 17];   // logit [n][B] pad 17
  __shared__ float s_l2[288 * 17];   // gate->softmax r [n][B] pad 17
  __shared__ float s_au[288];
  __shared__ float s_mu[16 * 9], s_rs[16 * 9];  // [B][kk]
  __shared__ float s_cw[256];        // transposed [c][B]
  __shared__ float s_cb[16], s_sw[81], s_sb[9], s_ga[32], s_be[32];
  __shared__ float s_as[16];
  __shared__ float s_aus;

  int tid = threadIdx.x;
  int row = blockIdx.x;
  int b = row / 196, l = row % 196, i0 = l / 14, j0 = l % 14;

  { int r = tid >> 4, c = tid & 15; s_cw[c * 16 + r] = cpose2_w[r * 16 + c]; }
  if (tid < 16) s_cb[tid] = cpose2_b[tid];
  if (tid < 81) s_sw[tid] = sp_w[tid];
  if (tid < 9)  s_sb[tid] = sp_b[tid];
  if (tid < 32) { s_ga[tid] = ln_g[tid]; s_be[tid] = ln_b[tid]; }

  // unfold pose -> pu [n=kk*32+a][c]
  for (int idx = tid; idx < 4608; idx += 256) {
    int n = idx >> 4, c = idx & 15;
    int a = n & 31, kk = n >> 5;
    int ki = kk / 3, kj = kk - 3 * ki;
    int yy = i0 + ki - 1, xx = j0 + kj - 1;
    float v = 0.f;
    if (yy >= 0 && yy < 14 && xx >= 0 && xx < 14)
      v = pose[((b * 512 + a * 16 + c) * 14 + yy) * 14 + xx];
    s_pu[n * 17 + c] = v;
  }
  // unfold a -> au [n]
  for (int n = tid; n < 288; n += 256) {
    int a = n & 31, kk = n >> 5;
    int ki = kk / 3, kj = kk - 3 * ki;
    int yy = i0 + ki - 1, xx = j0 + kj - 1;
    float v = 0.f;
    if (yy >= 0 && yy < 14 && xx >= 0 && xx < 14)
      v = a_img[((b * 32 + a) * 14 + yy) * 14 + xx];
    s_au[n] = v;
  }
  __syncthreads();

  // logit = pu @ cpose2_w^T + b
  for (int idx = tid; idx < 4608; idx += 256) {
    int n = idx >> 4, B = idx & 15;
    float acc = s_cb[B];
#pragma unroll
    for (int c = 0; c < 16; ++c) acc += s_pu[n * 17 + c] * s_cw[c * 16 + B];
    s_lg[n * 17 + B] = acc;
  }
  __syncthreads();

  // LayerNorm stats over a (32) per (kk,B)
  if (tid < 144) {
    int kk = tid >> 4, B = tid & 15;
    float s = 0.f, s2 = 0.f;
    for (int a = 0; a < 32; ++a) {
      float v = s_lg[(kk * 32 + a) * 17 + B];
      s += v; s2 += v * v;
    }
    float mu = s * (1.f / 32.f);
    float var = s2 * (1.f / 32.f) - mu * mu;
    s_mu[B * 9 + kk] = mu;
    s_rs[B * 9 + kk] = rsqrtf(var + 1e-5f);
  }
  __syncthreads();

  // spatial gate: mix over kk, gelu, logit_final = 2*logit + gelu_out
  for (int idx = tid; idx < 4608; idx += 256) {
    int n = idx >> 4, B = idx & 15;
    int o = n >> 5, a = n & 31;
    float acc = s_sb[o];
#pragma unroll
    for (int i2 = 0; i2 < 9; ++i2) {
      float v = s_lg[(i2 * 32 + a) * 17 + B];
      float gn = (v - s_mu[B * 9 + i2]) * s_rs[B * 9 + i2] * s_ga[a] + s_be[a];
      acc += s_sw[o * 9 + i2] * gn;
    }
    float ge = 0.5f * acc * (1.f + erff(acc * 0.70710678118654752f));
    s_l2[n * 17 + B] = 2.f * s_lg[n * 17 + B] + ge;
  }
  __syncthreads();

  // softmax over B per n -> r (in place)
  for (int n = tid; n < 288; n += 256) {
    float m = -1e30f;
#pragma unroll
    for (int B = 0; B < 16; ++B) m = fmaxf(m, s_l2[n * 17 + B]);
    float sum = 0.f;
#pragma unroll
    for (int B = 0; B < 16; ++B) {
      float e = expf(s_l2[n * 17 + B] - m);
      s_l2[n * 17 + B] = e;
      sum += e;
    }
    float inv = 1.f / sum;
#pragma unroll
    for (int B = 0; B < 16; ++B) s_l2[n * 17 + B] *= inv;
  }
  __syncthreads();

  // ar_sum[B] and au_sum
  if (tid < 16) {
    float s = 0.f;
    for (int n = 0; n < 288; ++n) s += s_au[n] * s_l2[n * 17 + tid];
    s_as[tid] = s;
  } else if (tid == 16) {
    float s = 0.f;
    for (int n = 0; n < 288; ++n) s += s_au[n];
    s_aus = s;
  }
  __syncthreads();

  if (tid < 16) out_a[(b * 16 + tid) * 196 + l] = s_as[tid] / s_aus;

  // coeff and pu to workspace
  for (int idx = tid; idx < 4608; idx += 256) {
    int n = idx >> 4, B = idx & 15;
    ws_co[row * 4608 + idx] = s_au[n] * s_l2[n * 17 + B] / s_as[B];
    ws_pu[row * 4608 + idx] = s_pu[n * 17 + B];  // B doubles as c index
  }
}

// ---------------------------------------------------------------------------
// Kernel 2: per (row, d) block.  x = gelu(pu @ mpose_w_d^T + b_d) [288,16],
// y = x + h_d (.) x (288-tap circular FIR), po[B,d] = sum_n coeff[n,B] y[n,B].
// ---------------------------------------------------------------------------
__global__ __launch_bounds__(256) void k_filter(
    const float* __restrict__ mpose_w, const float* __restrict__ mpose_b,
    const float* __restrict__ h2g, const float* __restrict__ ws_pu,
    const float* __restrict__ ws_co, float* __restrict__ out_po) {
  __shared__ float s_pu[288 * 17];                 // [n][c]
  __shared__ alignas(16) float s_x2[16 * 580];     // [b_][m] doubled (576) + pad
  __shared__ alignas(16) float s_h[576];
  __shared__ float s_mw[256];                      // transposed [c][b_]
  __shared__ float s_mb[16];
  __shared__ float s_part[256];

  int tid = threadIdx.x;
  int row = blockIdx.x, d = blockIdx.y;
  int b = row / 196, l = row % 196;

  { int b2 = tid >> 4, c = tid & 15; s_mw[c * 16 + b2] = mpose_w[(b2 * 16 + d) * 16 + c]; }
  if (tid < 16) s_mb[tid] = mpose_b[tid * 16 + d];
  for (int t = tid; t < 576; t += 256) s_h[t] = h2g[d * 576 + t];
  for (int idx = tid; idx < 4608; idx += 256)
    s_pu[(idx >> 4) * 17 + (idx & 15)] = ws_pu[row * 4608 + idx];
  __syncthreads();

  // x = gelu(pu @ mw^T + mb), stored doubled for circular indexing
  for (int idx = tid; idx < 4608; idx += 256) {
    int n = idx >> 4, b_ = idx & 15;
    float acc = s_mb[b_];
#pragma unroll
    for (int c = 0; c < 16; ++c) acc += s_pu[n * 17 + c] * s_mw[c * 16 + b_];
    float x = 0.5f * acc * (1.f + erff(acc * 0.70710678118654752f));
    s_x2[b_ * 580 + n] = x;
    s_x2[b_ * 580 + n + 288] = x;
  }
  __syncthreads();

  // FIR + contraction. task = (chunk of 8 outputs) x (b_); b_ = tid&15 constant.
  float pp = 0.f;
  int b_ = tid & 15;
  const float* xrow = &s_x2[b_ * 580];
  const float* cog = ws_co + row * 4608;
  for (int task = tid; task < 576; task += 256) {
    int c0 = (task >> 4) * 8;
    float acc[8] = {0.f, 0.f, 0.f, 0.f, 0.f, 0.f, 0.f, 0.f};
#pragma unroll 2
    for (int k = 0; k < 72; ++k) {
      float4 hv = *reinterpret_cast<const float4*>(&s_h[4 * k]);
      int base0 = c0 - 4 * k + 284;  // = c0 - (4k+3) - 1 + 288, 16B aligned
      float4 xa = *reinterpret_cast<const float4*>(&xrow[base0]);
      float4 xb = *reinterpret_cast<const float4*>(&xrow[base0 + 4]);
      float4 xc = *reinterpret_cast<const float4*>(&xrow[base0 + 8]);
      float hh[4] = {hv.x, hv.y, hv.z, hv.w};
      float z[12] = {xa.x, xa.y, xa.z, xa.w, xb.x, xb.y, xb.z, xb.w,
                     xc.x, xc.y, xc.z, xc.w};
#pragma unroll
      for (int j = 0; j < 8; ++j) {
#pragma unroll
        for (int s = 0; s < 4; ++s) acc[j] += hh[s] * z[j - s + 4];
      }
    }
#pragma unroll
    for (int j = 0; j < 8; ++j) {
      float y = acc[j] + xrow[c0 + j];               // +identity (residual)
      pp += y * cog[(c0 + j) * 16 + b_];
    }
  }
  s_part[tid] = pp;
  __syncthreads();
  if (tid < 16) {
    float s = 0.f;
#pragma unroll
    for (int q = 0; q < 16; ++q) s += s_part[tid + 16 * q];
    out_po[((b * 256) + tid * 16 + d) * 196 + l] = s;
  }
}

// ---------------------------------------------------------------------------
extern "C" void kernel_launch(void* const* d_in, const int* in_sizes, int n_in,
                              void* d_out, int out_size, void* d_ws, size_t ws_size,
                              hipStream_t stream) {
  const float* a_img    = (const float*)d_in[0];
  const float* pose     = (const float*)d_in[1];
  const float* mpose_w  = (const float*)d_in[2];
  const float* mpose_b  = (const float*)d_in[3];
  const float* cpose2_w = (const float*)d_in[4];
  const float* cpose2_b = (const float*)d_in[5];
  const float* cw       = (const float*)d_in[6];
  const float* ln_g     = (const float*)d_in[7];
  const float* ln_b     = (const float*)d_in[8];
  const float* sp_w     = (const float*)d_in[9];
  const float* sp_b     = (const float*)d_in[10];

  float* out = (float*)d_out;
  float* w = (float*)d_ws;
  float* ws_pu = w;                      // 784*4608 f32
  float* ws_co = w + 784 * 4608;         // 784*4608 f32
  float* h2    = w + 2 * 784 * 4608;     // 16*576 f32

  hipLaunchKernelGGL(k_htab, dim3(16), dim3(256), 0, stream, cw, h2);
  hipLaunchKernelGGL(k_rowprep, dim3(784), dim3(256), 0, stream,
                     a_img, pose, cpose2_w, cpose2_b, ln_g, ln_b, sp_w, sp_b,
                     out, ws_pu, ws_co);
  hipLaunchKernelGGL(k_filter, dim3(784, 16), dim3(256), 0, stream,
                     mpose_w, mpose_b, h2, ws_pu, ws_co, out + 12544);
}

// Round 2
// 478.571 us; speedup vs baseline: 2.4070x; 2.4070x over previous
//
#include <hip/hip_runtime.h>
#include <math.h>

// A=32, B=16, C=16, D=16, KK=9, KKA=288, BSZ=4, L=196, BL=784
// po = identity-term (exact f32, in k_rowprep) + G-term via MFMA:
//   G_d = H_d @ coeff  (H_d[t,n] = h_d[(n-t) mod 288], row-invariant),
//   po_G[b_,d] = sum_t x[t,b_,d] * G_d[t,b_].

typedef __attribute__((ext_vector_type(8))) short bf16x8;
typedef __attribute__((ext_vector_type(4))) float f32x4;

__device__ inline float bf2f(unsigned short u) {
  union { unsigned int i; float f; } v; v.i = ((unsigned int)u) << 16; return v.f;
}
__device__ inline unsigned short f2bf(float f) {
  union { float f; unsigned int i; } v; v.f = f;
  unsigned int r = v.i + 0x7FFFu + ((v.i >> 16) & 1u);
  return (unsigned short)(r >> 16);
}

// ---------------------------------------------------------------------------
// Kernel 0: h table -> fragment-ordered H_d (bf16) for MFMA A-operand.
// ws_H layout: [d][mt 18][kk 9][lane 64][j 8] bf16, value = H_d[t,n],
//   t = mt*16 + (lane&15), n = kk*32 + (lane>>4)*8 + j.
// ---------------------------------------------------------------------------
__global__ __launch_bounds__(256) void k_htab(const float* __restrict__ cw,
                                              unsigned short* __restrict__ ws_H) {
  __shared__ float s_h2[576];
  int d = blockIdx.x, tid = threadIdx.x;
  for (int t = tid; t < 288; t += 256) {
    float acc = cw[(0 * 16 + d) * 2 + 0] +
                ((t & 1) ? -1.f : 1.f) * cw[(144 * 16 + d) * 2 + 0];
    for (int f = 1; f < 144; ++f) {
      int m = (f * t) % 288;
      float th = (float)m * (6.283185307179586f / 288.f);
      float sn, cs;
      sincosf(th, &sn, &cs);
      acc += 2.f * (cw[(f * 16 + d) * 2 + 0] * cs - cw[(f * 16 + d) * 2 + 1] * sn);
    }
    float h = acc * (1.f / 288.f);
    s_h2[t] = h;
    s_h2[t + 288] = h;
  }
  __syncthreads();
  unsigned short* dst = ws_H + d * 82944;
  for (int idx = tid; idx < 82944; idx += 256) {
    int j = idx & 7, l = (idx >> 3) & 63;
    int kk = (idx >> 9) % 9, mt = (idx >> 9) / 9;
    int m = l & 15, g = l >> 4;
    int n = kk * 32 + g * 8 + j, t = mt * 16 + m;
    dst[idx] = f2bf(s_h2[n - t + 288]);
  }
}

// ---------------------------------------------------------------------------
// Kernel 1: per-row prep. Produces out_a, identity part of out_po (exact f32),
// ws_pu bf16 [row][t][c], ws_cb bf16 fragments [row][kk][g][b_][j].
// ---------------------------------------------------------------------------
__global__ __launch_bounds__(256) void k_rowprep(
    const float* __restrict__ a_img, const float* __restrict__ pose,
    const float* __restrict__ cpose2_w, const float* __restrict__ cpose2_b,
    const float* __restrict__ ln_g, const float* __restrict__ ln_b,
    const float* __restrict__ sp_w, const float* __restrict__ sp_b,
    const float* __restrict__ mpose_w, const float* __restrict__ mpose_b,
    float* __restrict__ out_a, float* __restrict__ out_po,
    unsigned short* __restrict__ ws_pu, unsigned short* __restrict__ ws_cb) {
  __shared__ float s_pu[288 * 17];
  __shared__ float s_lg[288 * 17];
  __shared__ float s_l2[288 * 17];
  __shared__ float s_au[288];
  __shared__ float s_mu[16 * 9], s_rs[16 * 9];
  __shared__ float s_cw[256];
  __shared__ float s_cb[16], s_sw[81], s_sb[9], s_ga[32], s_be[32];
  __shared__ float s_as[16];
  __shared__ float s_aus;

  int tid = threadIdx.x;
  int row = blockIdx.x;
  int b = row / 196, l = row % 196, i0 = l / 14, j0 = l % 14;

  { int r = tid >> 4, c = tid & 15; s_cw[c * 16 + r] = cpose2_w[r * 16 + c]; }
  if (tid < 16) s_cb[tid] = cpose2_b[tid];
  if (tid < 81) s_sw[tid] = sp_w[tid];
  if (tid < 9)  s_sb[tid] = sp_b[tid];
  if (tid < 32) { s_ga[tid] = ln_g[tid]; s_be[tid] = ln_b[tid]; }

  for (int idx = tid; idx < 4608; idx += 256) {
    int n = idx >> 4, c = idx & 15;
    int a = n & 31, kk = n >> 5;
    int ki = kk / 3, kj = kk - 3 * ki;
    int yy = i0 + ki - 1, xx = j0 + kj - 1;
    float v = 0.f;
    if (yy >= 0 && yy < 14 && xx >= 0 && xx < 14)
      v = pose[((b * 512 + a * 16 + c) * 14 + yy) * 14 + xx];
    s_pu[n * 17 + c] = v;
  }
  for (int n = tid; n < 288; n += 256) {
    int a = n & 31, kk = n >> 5;
    int ki = kk / 3, kj = kk - 3 * ki;
    int yy = i0 + ki - 1, xx = j0 + kj - 1;
    float v = 0.f;
    if (yy >= 0 && yy < 14 && xx >= 0 && xx < 14)
      v = a_img[((b * 32 + a) * 14 + yy) * 14 + xx];
    s_au[n] = v;
  }
  __syncthreads();

  for (int idx = tid; idx < 4608; idx += 256) {
    int n = idx >> 4, B = idx & 15;
    float acc = s_cb[B];
#pragma unroll
    for (int c = 0; c < 16; ++c) acc += s_pu[n * 17 + c] * s_cw[c * 16 + B];
    s_lg[n * 17 + B] = acc;
  }
  __syncthreads();

  if (tid < 144) {
    int kk = tid >> 4, B = tid & 15;
    float s = 0.f, s2 = 0.f;
    for (int a = 0; a < 32; ++a) {
      float v = s_lg[(kk * 32 + a) * 17 + B];
      s += v; s2 += v * v;
    }
    float mu = s * (1.f / 32.f);
    float var = s2 * (1.f / 32.f) - mu * mu;
    s_mu[B * 9 + kk] = mu;
    s_rs[B * 9 + kk] = rsqrtf(var + 1e-5f);
  }
  __syncthreads();

  for (int idx = tid; idx < 4608; idx += 256) {
    int n = idx >> 4, B = idx & 15;
    int o = n >> 5, a = n & 31;
    float acc = s_sb[o];
#pragma unroll
    for (int i2 = 0; i2 < 9; ++i2) {
      float v = s_lg[(i2 * 32 + a) * 17 + B];
      float gn = (v - s_mu[B * 9 + i2]) * s_rs[B * 9 + i2] * s_ga[a] + s_be[a];
      acc += s_sw[o * 9 + i2] * gn;
    }
    float ge = 0.5f * acc * (1.f + erff(acc * 0.70710678118654752f));
    s_l2[n * 17 + B] = 2.f * s_lg[n * 17 + B] + ge;
  }
  __syncthreads();

  for (int n = tid; n < 288; n += 256) {
    float m = -1e30f;
#pragma unroll
    for (int B = 0; B < 16; ++B) m = fmaxf(m, s_l2[n * 17 + B]);
    float sum = 0.f;
#pragma unroll
    for (int B = 0; B < 16; ++B) {
      float e = expf(s_l2[n * 17 + B] - m);
      s_l2[n * 17 + B] = e;
      sum += e;
    }
    float inv = 1.f / sum;
#pragma unroll
    for (int B = 0; B < 16; ++B) s_l2[n * 17 + B] *= inv;
  }
  __syncthreads();

  if (tid < 16) {
    float s = 0.f;
    for (int n = 0; n < 288; ++n) s += s_au[n] * s_l2[n * 17 + tid];
    s_as[tid] = s;
  } else if (tid == 16) {
    float s = 0.f;
    for (int n = 0; n < 288; ++n) s += s_au[n];
    s_aus = s;
  }
  __syncthreads();

  if (tid < 16) out_a[(b * 16 + tid) * 196 + l] = s_as[tid] / s_aus;

  // coeff in place
  for (int idx = tid; idx < 4608; idx += 256) {
    int n = idx >> 4, B = idx & 15;
    s_l2[n * 17 + B] = s_au[n] * s_l2[n * 17 + B] / s_as[B];
  }
  __syncthreads();

  // ws_cb bf16 fragments: idx = ((kk*4+g)*16 + b_)*8 + j, n = kk*32+g*8+j
  for (int idx = tid; idx < 4608; idx += 256) {
    int j = idx & 7, B = (idx >> 3) & 15, g = (idx >> 7) & 3, kk = idx >> 9;
    int n = kk * 32 + g * 8 + j;
    ws_cb[row * 4608 + idx] = f2bf(s_l2[n * 17 + B]);
  }
  // ws_pu bf16 [t][c]
  for (int idx = tid; idx < 4608; idx += 256) {
    ws_pu[row * 4608 + idx] = f2bf(s_pu[(idx >> 4) * 17 + (idx & 15)]);
  }

  // identity term (exact f32): thread (d,b_) over t
  {
    int d = tid >> 4, B = tid & 15;
    const float* mwp = mpose_w + (B * 16 + d) * 16;
    float mw[16];
#pragma unroll
    for (int c = 0; c < 16; ++c) mw[c] = mwp[c];
    float mb = mpose_b[B * 16 + d];
    float po = 0.f;
    for (int t = 0; t < 288; ++t) {
      float acc = mb;
#pragma unroll
      for (int c = 0; c < 16; ++c) acc += s_pu[t * 17 + c] * mw[c];
      float x = 0.5f * acc * (1.f + erff(acc * 0.70710678118654752f));
      po += s_l2[t * 17 + B] * x;
    }
    out_po[((b * 256) + B * 16 + d) * 196 + l] = po;
  }
}

// ---------------------------------------------------------------------------
// Kernel 2: G-term. grid(196, 16): 4 rows/block (1 per wave), d = blockIdx.y.
// Wave: x = gelu(pu@mw_d^T) bf16 in LDS; GEMM H_d[288,288] x coeff[288,16]
// streamed per M-tile pair; contract with x; += into out_po. No barriers.
// ---------------------------------------------------------------------------
__global__ __launch_bounds__(256) void k_gterm(
    const unsigned short* __restrict__ ws_H,
    const unsigned short* __restrict__ ws_pu,
    const unsigned short* __restrict__ ws_cb,
    const float* __restrict__ mpose_w, const float* __restrict__ mpose_b,
    float* __restrict__ out_po) {
  __shared__ unsigned short s_pu[4 * 4608];       // [w][t][c]
  __shared__ unsigned short s_x[4 * 288 * 18];    // [w][t][b_], stride 18

  int tid = threadIdx.x;
  int w = tid >> 6, l = tid & 63;
  int row = blockIdx.x * 4 + w, d = blockIdx.y;
  int b_ = l & 15, g = l >> 4;

  // stage pu (wave-local, 9 x 16B per lane)
  {
    const uint4* src = (const uint4*)(ws_pu + row * 4608);
    uint4* dst = (uint4*)(s_pu + w * 4608);
#pragma unroll
    for (int i = 0; i < 9; ++i) dst[l + 64 * i] = src[l + 64 * i];
  }

  float mw[16];
  {
    const float* mwp = mpose_w + (b_ * 16 + d) * 16;
#pragma unroll
    for (int c = 0; c < 16; ++c) mw[c] = mwp[c];
  }
  float mb = mpose_b[b_ * 16 + d];

  // x for own row -> LDS bf16
  const unsigned short* pu = s_pu + w * 4608;
  unsigned short* xw = s_x + w * (288 * 18);
  for (int i = 0; i < 72; ++i) {
    int t = i * 4 + g;
    float acc = mb;
#pragma unroll
    for (int c = 0; c < 16; ++c) acc += bf2f(pu[t * 16 + c]) * mw[c];
    float x = 0.5f * acc * (1.f + erff(acc * 0.70710678118654752f));
    xw[t * 18 + b_] = f2bf(x);
  }

  // GEMM + contraction
  const bf16x8* aH = (const bf16x8*)ws_H + d * (18 * 9 * 64);
  const bf16x8* bC = (const bf16x8*)ws_cb + row * (9 * 64);
  float po = 0.f;
  for (int mtp = 0; mtp < 9; ++mtp) {
    int mt0 = mtp * 2;
    f32x4 acc0 = {0.f, 0.f, 0.f, 0.f}, acc1 = {0.f, 0.f, 0.f, 0.f};
#pragma unroll 3
    for (int kk = 0; kk < 9; ++kk) {
      bf16x8 a0 = aH[(mt0 * 9 + kk) * 64 + l];
      bf16x8 a1 = aH[((mt0 + 1) * 9 + kk) * 64 + l];
      bf16x8 bb = bC[kk * 64 + l];
      acc0 = __builtin_amdgcn_mfma_f32_16x16x32_bf16(a0, bb, acc0, 0, 0, 0);
      acc1 = __builtin_amdgcn_mfma_f32_16x16x32_bf16(a1, bb, acc1, 0, 0, 0);
    }
#pragma unroll
    for (int r = 0; r < 4; ++r) {
      int t0 = mt0 * 16 + g * 4 + r;
      po += acc0[r] * bf2f(xw[t0 * 18 + b_]);
      po += acc1[r] * bf2f(xw[(t0 + 16) * 18 + b_]);
    }
  }
  po += __shfl_xor(po, 16);
  po += __shfl_xor(po, 32);
  if (l < 16) {
    int bb = row / 196, loc = row % 196;
    float* p = out_po + ((bb * 256) + l * 16 + d) * 196 + loc;
    *p += po;
  }
}

// ---------------------------------------------------------------------------
extern "C" void kernel_launch(void* const* d_in, const int* in_sizes, int n_in,
                              void* d_out, int out_size, void* d_ws, size_t ws_size,
                              hipStream_t stream) {
  const float* a_img    = (const float*)d_in[0];
  const float* pose     = (const float*)d_in[1];
  const float* mpose_w  = (const float*)d_in[2];
  const float* mpose_b  = (const float*)d_in[3];
  const float* cpose2_w = (const float*)d_in[4];
  const float* cpose2_b = (const float*)d_in[5];
  const float* cw       = (const float*)d_in[6];
  const float* ln_g     = (const float*)d_in[7];
  const float* ln_b     = (const float*)d_in[8];
  const float* sp_w     = (const float*)d_in[9];
  const float* sp_b     = (const float*)d_in[10];

  float* out = (float*)d_out;
  unsigned short* ws_H  = (unsigned short*)d_ws;     // 16*82944
  unsigned short* ws_pu = ws_H + 16 * 82944;         // 784*4608
  unsigned short* ws_cb = ws_pu + 784 * 4608;        // 784*4608

  hipLaunchKernelGGL(k_htab, dim3(16), dim3(256), 0, stream, cw, ws_H);
  hipLaunchKernelGGL(k_rowprep, dim3(784), dim3(256), 0, stream,
                     a_img, pose, cpose2_w, cpose2_b, ln_g, ln_b, sp_w, sp_b,
                     mpose_w, mpose_b, out, out + 12544, ws_pu, ws_cb);
  hipLaunchKernelGGL(k_gterm, dim3(196, 16), dim3(256), 0, stream,
                     ws_H, ws_pu, ws_cb, mpose_w, mpose_b, out + 12544);
}

// Round 3
// 321.005 us; speedup vs baseline: 3.5884x; 1.4909x over previous
//
#include <hip/hip_runtime.h>
#include <math.h>

// A=32, B=16, C=16, D=16, KK=9, KKA=288, BSZ=4, L=196, BL=784
// po[b_,d] = sum_t (G_d[t,b_] + coeff[t,b_]) * x[t,b_,d]
//   G_d = H_d @ coeff,  H_d[t,n] = h_d[(n-t) mod 288]  (row-invariant)
//   x = gelu(pu @ mpose_w_d^T + mb_d)   computed via MFMA, same C/D layout as G.

typedef __attribute__((ext_vector_type(8))) short bf16x8;
typedef __attribute__((ext_vector_type(4))) float f32x4;

__device__ inline float bf2f(unsigned short u) {
  union { unsigned int i; float f; } v; v.i = ((unsigned int)u) << 16; return v.f;
}
__device__ inline unsigned short f2bf(float f) {
  union { float f; unsigned int i; } v; v.f = f;
  unsigned int r = v.i + 0x7FFFu + ((v.i >> 16) & 1u);
  return (unsigned short)(r >> 16);
}

// ---------------------------------------------------------------------------
// Kernel 0: h table -> fragment-ordered H_d (bf16) for MFMA A-operand.
// ws_H: [d][mt 18][kk 9][lane 64][j 8], value H_d[t,n],
//   t = mt*16 + (l&15), n = kk*32 + (l>>4)*8 + j.
// ---------------------------------------------------------------------------
__global__ __launch_bounds__(256) void k_htab(const float* __restrict__ cw,
                                              unsigned short* __restrict__ ws_H) {
  __shared__ float s_h2[576];
  int d = blockIdx.x, tid = threadIdx.x;
  for (int t = tid; t < 288; t += 256) {
    float acc = cw[(0 * 16 + d) * 2 + 0] +
                ((t & 1) ? -1.f : 1.f) * cw[(144 * 16 + d) * 2 + 0];
    for (int f = 1; f < 144; ++f) {
      int m = (f * t) % 288;
      float th = (float)m * (6.283185307179586f / 288.f);
      float sn, cs;
      sincosf(th, &sn, &cs);
      acc += 2.f * (cw[(f * 16 + d) * 2 + 0] * cs - cw[(f * 16 + d) * 2 + 1] * sn);
    }
    float h = acc * (1.f / 288.f);
    s_h2[t] = h;
    s_h2[t + 288] = h;
  }
  __syncthreads();
  unsigned short* dst = ws_H + d * 82944;
  for (int idx = tid; idx < 82944; idx += 256) {
    int j = idx & 7, l = (idx >> 3) & 63;
    int kk = (idx >> 9) % 9, mt = (idx >> 9) / 9;
    int m = l & 15, g = l >> 4;
    int n = kk * 32 + g * 8 + j, t = mt * 16 + m;
    dst[idx] = f2bf(s_h2[n - t + 288]);
  }
}

// ---------------------------------------------------------------------------
// Kernel 1: per-row prep (round-1 structure, no identity loop).
// Writes: out_a; ws_cf f32 coeff natural layout [row][n*16+b_];
//         ws_pu bf16 compact A-frags [row][mt 18][l 32][j 8]
//           value pu[t = mt*16 + (l&15), c = (l>>4)*8 + j]  (c < 16 only).
// ---------------------------------------------------------------------------
__global__ __launch_bounds__(256) void k_rowprep(
    const float* __restrict__ a_img, const float* __restrict__ pose,
    const float* __restrict__ cpose2_w, const float* __restrict__ cpose2_b,
    const float* __restrict__ ln_g, const float* __restrict__ ln_b,
    const float* __restrict__ sp_w, const float* __restrict__ sp_b,
    float* __restrict__ out_a, unsigned short* __restrict__ ws_pu,
    float* __restrict__ ws_cf) {
  __shared__ float s_pu[288 * 17];
  __shared__ float s_lg[288 * 17];
  __shared__ float s_l2[288 * 17];
  __shared__ float s_au[288];
  __shared__ float s_mu[16 * 9], s_rs[16 * 9];
  __shared__ float s_cw[256];
  __shared__ float s_cb[16], s_sw[81], s_sb[9], s_ga[32], s_be[32];
  __shared__ float s_as[16];
  __shared__ float s_aus;

  int tid = threadIdx.x;
  int row = blockIdx.x;
  int b = row / 196, l = row % 196, i0 = l / 14, j0 = l % 14;

  { int r = tid >> 4, c = tid & 15; s_cw[c * 16 + r] = cpose2_w[r * 16 + c]; }
  if (tid < 16) s_cb[tid] = cpose2_b[tid];
  if (tid < 81) s_sw[tid] = sp_w[tid];
  if (tid < 9)  s_sb[tid] = sp_b[tid];
  if (tid < 32) { s_ga[tid] = ln_g[tid]; s_be[tid] = ln_b[tid]; }

  for (int idx = tid; idx < 4608; idx += 256) {
    int n = idx >> 4, c = idx & 15;
    int a = n & 31, kk = n >> 5;
    int ki = kk / 3, kj = kk - 3 * ki;
    int yy = i0 + ki - 1, xx = j0 + kj - 1;
    float v = 0.f;
    if (yy >= 0 && yy < 14 && xx >= 0 && xx < 14)
      v = pose[((b * 512 + a * 16 + c) * 14 + yy) * 14 + xx];
    s_pu[n * 17 + c] = v;
  }
  for (int n = tid; n < 288; n += 256) {
    int a = n & 31, kk = n >> 5;
    int ki = kk / 3, kj = kk - 3 * ki;
    int yy = i0 + ki - 1, xx = j0 + kj - 1;
    float v = 0.f;
    if (yy >= 0 && yy < 14 && xx >= 0 && xx < 14)
      v = a_img[((b * 32 + a) * 14 + yy) * 14 + xx];
    s_au[n] = v;
  }
  __syncthreads();

  for (int idx = tid; idx < 4608; idx += 256) {
    int n = idx >> 4, B = idx & 15;
    float acc = s_cb[B];
#pragma unroll
    for (int c = 0; c < 16; ++c) acc += s_pu[n * 17 + c] * s_cw[c * 16 + B];
    s_lg[n * 17 + B] = acc;
  }
  __syncthreads();

  if (tid < 144) {
    int kk = tid >> 4, B = tid & 15;
    float s = 0.f, s2 = 0.f;
    for (int a = 0; a < 32; ++a) {
      float v = s_lg[(kk * 32 + a) * 17 + B];
      s += v; s2 += v * v;
    }
    float mu = s * (1.f / 32.f);
    float var = s2 * (1.f / 32.f) - mu * mu;
    s_mu[B * 9 + kk] = mu;
    s_rs[B * 9 + kk] = rsqrtf(var + 1e-5f);
  }
  __syncthreads();

  for (int idx = tid; idx < 4608; idx += 256) {
    int n = idx >> 4, B = idx & 15;
    int o = n >> 5, a = n & 31;
    float acc = s_sb[o];
#pragma unroll
    for (int i2 = 0; i2 < 9; ++i2) {
      float v = s_lg[(i2 * 32 + a) * 17 + B];
      float gn = (v - s_mu[B * 9 + i2]) * s_rs[B * 9 + i2] * s_ga[a] + s_be[a];
      acc += s_sw[o * 9 + i2] * gn;
    }
    float ge = 0.5f * acc * (1.f + erff(acc * 0.70710678118654752f));
    s_l2[n * 17 + B] = 2.f * s_lg[n * 17 + B] + ge;
  }
  __syncthreads();

  for (int n = tid; n < 288; n += 256) {
    float m = -1e30f;
#pragma unroll
    for (int B = 0; B < 16; ++B) m = fmaxf(m, s_l2[n * 17 + B]);
    float sum = 0.f;
#pragma unroll
    for (int B = 0; B < 16; ++B) {
      float e = expf(s_l2[n * 17 + B] - m);
      s_l2[n * 17 + B] = e;
      sum += e;
    }
    float inv = 1.f / sum;
#pragma unroll
    for (int B = 0; B < 16; ++B) s_l2[n * 17 + B] *= inv;
  }
  __syncthreads();

  if (tid < 16) {
    float s = 0.f;
    for (int n = 0; n < 288; ++n) s += s_au[n] * s_l2[n * 17 + tid];
    s_as[tid] = s;
  } else if (tid == 16) {
    float s = 0.f;
    for (int n = 0; n < 288; ++n) s += s_au[n];
    s_aus = s;
  }
  __syncthreads();

  if (tid < 16) out_a[(b * 16 + tid) * 196 + l] = s_as[tid] / s_aus;

  // coeff in place
  for (int idx = tid; idx < 4608; idx += 256) {
    int n = idx >> 4, B = idx & 15;
    s_l2[n * 17 + B] = s_au[n] * s_l2[n * 17 + B] / s_as[B];
  }
  __syncthreads();

  // coeff f32, natural layout
  for (int idx = tid; idx < 4608; idx += 256)
    ws_cf[row * 4608 + idx] = s_l2[(idx >> 4) * 17 + (idx & 15)];
  // pu compact A-frags
  for (int idx = tid; idx < 4608; idx += 256) {
    int j = idx & 7, l2 = (idx >> 3) & 31, mt = idx >> 8;
    int m = l2 & 15, c = (l2 >> 4) * 8 + j;
    ws_pu[row * 4608 + idx] = f2bf(s_pu[(mt * 16 + m) * 17 + c]);
  }
}

// ---------------------------------------------------------------------------
// Kernel 2: grid(98,16), 4 waves/block, each wave = 2 rows, d = blockIdx.y.
// All-register: x via MFMA (K padded 16->32), G via MFMA, epilogue in regs.
// ---------------------------------------------------------------------------
__global__ __launch_bounds__(256) void k_gterm(
    const unsigned short* __restrict__ ws_H,
    const unsigned short* __restrict__ ws_pu,
    const float* __restrict__ ws_cf,
    const float* __restrict__ mpose_w, const float* __restrict__ mpose_b,
    float* __restrict__ out_po) {
  int tid = threadIdx.x;
  int w = tid >> 6, l = tid & 63;
  int d = blockIdx.y;
  int p = blockIdx.x * 4 + w;          // row-pair id
  int row0 = p * 2, row1 = p * 2 + 1;
  int b_ = l & 15, g = l >> 4;

  const bf16x8 z8 = {0, 0, 0, 0, 0, 0, 0, 0};
  const f32x4 zf = {0.f, 0.f, 0.f, 0.f};

  // mpose_w B-frag (k = c, zero-padded c>=16)
  bf16x8 bmw = z8;
  if (g < 2) {
    const float* mp = mpose_w + (b_ * 16 + d) * 16 + g * 8;
#pragma unroll
    for (int j = 0; j < 8; ++j) bmw[j] = (short)f2bf(mp[j]);
  }
  float mb = mpose_b[b_ * 16 + d];

  const bf16x8* aH = (const bf16x8*)ws_H + d * (18 * 9 * 64);
  const bf16x8* aP0 = (const bf16x8*)ws_pu + row0 * 576;
  const bf16x8* aP1 = (const bf16x8*)ws_pu + row1 * 576;
  const float* cfr0 = ws_cf + row0 * 4608;
  const float* cfr1 = ws_cf + row1 * 4608;

  // coeff B-frags (bf16) gathered from f32 coeff (coalesced per 16-lane group)
  bf16x8 c0[9], c1[9];
#pragma unroll
  for (int kk = 0; kk < 9; ++kk) {
    bf16x8 v0 = z8, v1 = z8;
#pragma unroll
    for (int j = 0; j < 8; ++j) {
      int n = kk * 32 + g * 8 + j;
      v0[j] = (short)f2bf(cfr0[n * 16 + b_]);
      v1[j] = (short)f2bf(cfr1[n * 16 + b_]);
    }
    c0[kk] = v0; c1[kk] = v1;
  }

  float po0 = 0.f, po1 = 0.f;
  for (int mt = 0; mt < 18; ++mt) {
    // x pre-activation tiles (same C/D layout as G)
    bf16x8 ap0 = z8, ap1 = z8;
    if (g < 2) { ap0 = aP0[mt * 32 + l]; ap1 = aP1[mt * 32 + l]; }
    f32x4 xp0 = __builtin_amdgcn_mfma_f32_16x16x32_bf16(ap0, bmw, zf, 0, 0, 0);
    f32x4 xp1 = __builtin_amdgcn_mfma_f32_16x16x32_bf16(ap1, bmw, zf, 0, 0, 0);
    // G tiles
    f32x4 g0 = zf, g1 = zf;
#pragma unroll
    for (int kk = 0; kk < 9; ++kk) {
      bf16x8 a = aH[(mt * 9 + kk) * 64 + l];
      g0 = __builtin_amdgcn_mfma_f32_16x16x32_bf16(a, c0[kk], g0, 0, 0, 0);
      g1 = __builtin_amdgcn_mfma_f32_16x16x32_bf16(a, c1[kk], g1, 0, 0, 0);
    }
    // epilogue: po += (G + coeff_f32) * gelu(xpre + mb)
#pragma unroll
    for (int r = 0; r < 4; ++r) {
      int t = mt * 16 + (l >> 4) * 4 + r;
      float s0 = xp0[r] + mb, s1 = xp1[r] + mb;
      float x0 = 0.5f * s0 * (1.f + erff(s0 * 0.70710678118654752f));
      float x1 = 0.5f * s1 * (1.f + erff(s1 * 0.70710678118654752f));
      po0 += (g0[r] + cfr0[t * 16 + b_]) * x0;
      po1 += (g1[r] + cfr1[t * 16 + b_]) * x1;
    }
  }
  po0 += __shfl_xor(po0, 16);
  po0 += __shfl_xor(po0, 32);
  po1 += __shfl_xor(po1, 16);
  po1 += __shfl_xor(po1, 32);
  if (l < 16) {
    int bb0 = row0 / 196, lc0 = row0 % 196;
    out_po[((bb0 * 256) + l * 16 + d) * 196 + lc0] = po0;
    int bb1 = row1 / 196, lc1 = row1 % 196;
    out_po[((bb1 * 256) + l * 16 + d) * 196 + lc1] = po1;
  }
}

// ---------------------------------------------------------------------------
extern "C" void kernel_launch(void* const* d_in, const int* in_sizes, int n_in,
                              void* d_out, int out_size, void* d_ws, size_t ws_size,
                              hipStream_t stream) {
  const float* a_img    = (const float*)d_in[0];
  const float* pose     = (const float*)d_in[1];
  const float* mpose_w  = (const float*)d_in[2];
  const float* mpose_b  = (const float*)d_in[3];
  const float* cpose2_w = (const float*)d_in[4];
  const float* cpose2_b = (const float*)d_in[5];
  const float* cw       = (const float*)d_in[6];
  const float* ln_g     = (const float*)d_in[7];
  const float* ln_b     = (const float*)d_in[8];
  const float* sp_w     = (const float*)d_in[9];
  const float* sp_b     = (const float*)d_in[10];

  float* out = (float*)d_out;
  unsigned short* ws_H  = (unsigned short*)d_ws;      // 16*82944 bf16 = 2.65 MB
  unsigned short* ws_pu = ws_H + 16 * 82944;          // 784*4608 bf16 = 7.2 MB
  float* ws_cf = (float*)(ws_pu + 784 * 4608);        // 784*4608 f32 = 14.5 MB

  hipLaunchKernelGGL(k_htab, dim3(16), dim3(256), 0, stream, cw, ws_H);
  hipLaunchKernelGGL(k_rowprep, dim3(784), dim3(256), 0, stream,
                     a_img, pose, cpose2_w, cpose2_b, ln_g, ln_b, sp_w, sp_b,
                     out, ws_pu, ws_cf);
  hipLaunchKernelGGL(k_gterm, dim3(98, 16), dim3(256), 0, stream,
                     ws_H, ws_pu, ws_cf, mpose_w, mpose_b, out + 12544);
}